// Round 4
// baseline (435.559 us; speedup 1.0000x reference)
//
#include <hip/hip_runtime.h>

#define GAT_N 50000
#define GAT_D 256
#define GAT_T 3
#define GAT_E 250000
#define GAT_B (GAT_T*GAT_N)      // 150000 (node,type) buckets
#define GAT_TOTE (GAT_T*GAT_E)   // 750000 edges total
#define GAT_COLS (GAT_T*GAT_D)   // 768 fused output columns
#define GAT_SLOPE 0.2f

typedef unsigned short u16;
typedef unsigned int u32;
typedef __attribute__((ext_vector_type(8))) short s16x8;     // raw bf16 storage
typedef __attribute__((ext_vector_type(8))) __bf16 bf16x8;   // MFMA operand
typedef __attribute__((ext_vector_type(4))) float f32x4;
typedef __attribute__((ext_vector_type(4))) u32 u32x4;

__device__ __forceinline__ u16 f2bf(float f) {
    u32 x = __builtin_bit_cast(u32, f);
    u32 r = (x + 0x7fffu + ((x >> 16) & 1u)) >> 16;   // RNE
    return (u16)r;
}
__device__ __forceinline__ float lo16(u32 w) {
    return __builtin_bit_cast(float, w << 16);
}
__device__ __forceinline__ float hi16(u32 w) {
    return __builtin_bit_cast(float, w & 0xffff0000u);
}

// ---- tiny init: cnt/total zero (must precede fused prep+hist) -------------
__global__ void gat_zero(u32* __restrict__ cnt, u32* __restrict__ total) {
    int idx = blockIdx.x * 256 + threadIdx.x;
    if (idx == 0) *total = 0u;
    if (idx < GAT_B) cnt[idx] = 0u;
}

// ---- fused prep: W1/W2 -> bf16 transposed, z -> bf16, bias3, + HIST -------
// r4: hist fused in (random atomics overlap the streaming BW work; saves a
// full 750K-edge pass as a separate dispatch).
__global__ void gat_prep(const float* __restrict__ W1, const float* __restrict__ W2,
                         const float* __restrict__ z, const float* __restrict__ b1,
                         const float* __restrict__ b2, const int* __restrict__ ei,
                         u16* __restrict__ WT1b, u16* __restrict__ WT2b,
                         u16* __restrict__ zb, u32* __restrict__ cnt,
                         float* __restrict__ bias3)
{
    int idx = blockIdx.x * 256 + threadIdx.x;
    if (idx < GAT_T * GAT_D * GAT_D) {               // 196608
        int t = idx >> 16, r = idx & 65535;
        int d = r >> 8, h = r & 255;
        WT1b[t * 65536 + h * 256 + d] = f2bf(W1[idx]);
        WT2b[t * 65536 + h * 256 + d] = f2bf(W2[idx]);
    }
    if (idx < 2 * GAT_D) {
        const float* bb = (idx < GAT_D) ? b1 : b2;
        int c = idx & 255;
        bias3[idx] = bb[c] + bb[GAT_D + c] + bb[2 * GAT_D + c];
    }
    if (idx < GAT_TOTE) {                            // fused hist
        int t = idx / GAT_E;
        int e = idx - t * GAT_E;
        int dst = ei[t * 2 * GAT_E + GAT_E + e];
        atomicAdd(&cnt[dst * GAT_T + t], 1u);
    }
    if (idx < GAT_N * GAT_D / 4) {
        f32x4 v = ((const f32x4*)z)[idx];
        ushort4 pk;
        pk.x = f2bf(v.x); pk.y = f2bf(v.y); pk.z = f2bf(v.z); pk.w = f2bf(v.w);
        ((ushort4*)zb)[idx] = pk;
    }
}

// one thread per NODE: contiguous slab for its 3 type-segments
__global__ void gat_alloc(const u32* __restrict__ cnt, u32* __restrict__ pos2,
                          u32* __restrict__ degp, u32* __restrict__ cur,
                          u32* __restrict__ total)
{
    int n = blockIdx.x * 256 + threadIdx.x;
    if (n >= GAT_N) return;
    u32 c0 = cnt[3 * n], c1 = cnt[3 * n + 1], c2 = cnt[3 * n + 2];
    u32 p = atomicAdd(total, c0 + c1 + c2);
    pos2[n] = p;
    degp[n] = c0 | (c1 << 8) | (c2 << 16);
    cur[3 * n]     = p;
    cur[3 * n + 1] = p + c0;
    cur[3 * n + 2] = p + c0 + c1;
}

// psrc stores ABSOLUTE H row (t*N+src)
__global__ void gat_scatter(const int* __restrict__ ei, u32* __restrict__ cur,
                            int* __restrict__ psrc)
{
    int idx = blockIdx.x * 256 + threadIdx.x;
    if (idx >= GAT_TOTE) return;
    int t = idx / GAT_E;
    int e = idx - t * GAT_E;
    int src = ei[t * 2 * GAT_E + e];
    int dst = ei[t * 2 * GAT_E + GAT_E + e];
    u32 slot = atomicAdd(&cur[dst * GAT_T + t], 1u);
    psrc[slot] = t * GAT_N + src;
}

// ================= LDS-staged MFMA GEMM (XOR-swizzled) + partial attn dots ==
// Swizzle: LDS[row][chunk j] = G[row][j ^ (row&7)] via permuted per-lane
// global source addr (keeps global_load_lds wave-uniform dest + coalescing).
// Grid swizzle: lin = (r/8)*48 + c*8 + (r%8) -> col siblings share an XCD.
// Dbuf K-loop, counted vmcnt (r3).
//
// r4: 512-thread / 8-wave blocks at the SAME 128x128 tile + 64 KB LDS.
// r3 post-mortem: 64 KB LDS -> 2 blocks/CU; with 256-thread blocks that was
// only 2 waves/SIMD -> ~85% stall (waves 27K cyc resident, ~4K busy).
// 8-wave blocks double waves/CU at constant LDS (16 waves/CU, 4/SIMD).
// Wave grid 2x4: wm row-half (64 rows), wn col-quarter (32 cols); acc 4x2.
__global__ __launch_bounds__(512, 4) void gat_gemm(
    const u16* __restrict__ A, const u16* __restrict__ WTb,
    u16* __restrict__ H, const float* __restrict__ as_in,
    const float* __restrict__ ad_in, float* __restrict__ part_src,
    float* __restrict__ part_dst)
{
    // decode XCD-grouped swizzle
    int lin = blockIdx.x;
    int g   = lin / 48;
    int rem = lin - g * 48;
    int bc  = rem >> 3;                 // col tile 0..5
    int br  = (g << 3) + (rem & 7);     // row slab 0..390
    if (br >= 391) return;

    __shared__ u16 Als[2][128 * 64];   // 2 x 16 KB
    __shared__ u16 Bls[2][128 * 64];   // 2 x 16 KB
    int tid  = threadIdx.x;
    int wave = tid >> 6, lane = tid & 63;
    int quad = lane >> 4, l16 = lane & 15;
    int wm = wave & 1, wn = wave >> 1;       // wm: row half, wn: col quarter
    int lrow = lane >> 3;                    // 0..7
    int swz  = ((lane & 7) ^ lrow) * 8;      // swizzled k-offset (u16)

    size_t arow0 = (size_t)br * 128;
    size_t brow0 = (size_t)bc * 128;

    // stage K-chunk ks into buffer buf: 4 global_load_lds per wave
    // (2 x 8-row groups x {A,B}); wave w covers rows [w*16, w*16+16).
    auto STAGE = [&](int buf, int ks) {
        int k0 = ks * 64;
        #pragma unroll
        for (int r = 0; r < 2; ++r) {
            int srow = wave * 16 + r * 8 + lrow;
            const u16* gA = A   + (arow0 + srow) * GAT_D + k0 + swz;
            const u16* gB = WTb + (brow0 + srow) * GAT_D + k0 + swz;
            u16* lA = &Als[buf][wave * 1024 + r * 512];   // wave-uniform dest
            u16* lB = &Bls[buf][wave * 1024 + r * 512];
#if defined(__has_builtin) && __has_builtin(__builtin_amdgcn_global_load_lds)
            __builtin_amdgcn_global_load_lds(
                (const __attribute__((address_space(1))) void*)gA,
                (__attribute__((address_space(3))) void*)lA, 16, 0, 0);
            __builtin_amdgcn_global_load_lds(
                (const __attribute__((address_space(1))) void*)gB,
                (__attribute__((address_space(3))) void*)lB, 16, 0, 0);
#else
            *(s16x8*)(lA + lane * 8) = *(const s16x8*)gA;
            *(s16x8*)(lB + lane * 8) = *(const s16x8*)gB;
#endif
        }
    };

    f32x4 acc[4][2] = {};

    STAGE(0, 0);
    #pragma unroll
    for (int ks = 0; ks < 4; ++ks) {
        int cur = ks & 1;
        if (ks < 3) {
            STAGE(cur ^ 1, ks + 1);
            // wait for buf[cur]'s 4 loads; buf[cur^1]'s 4 stay in flight
            asm volatile("s_waitcnt vmcnt(4)" ::: "memory");
        } else {
            asm volatile("s_waitcnt vmcnt(0)" ::: "memory");
        }
        __builtin_amdgcn_s_barrier();     // all waves' stage of cur complete

        #pragma unroll
        for (int kk = 0; kk < 2; ++kk) {
            int csw8 = ((kk * 4 + quad) ^ (l16 & 7)) * 8;   // row&7 == l16&7
            bf16x8 af[4], bf[2];
            #pragma unroll
            for (int i = 0; i < 4; ++i)
                af[i] = __builtin_bit_cast(bf16x8,
                    *(const s16x8*)(&Als[cur][(wm * 64 + i * 16 + l16) * 64 + csw8]));
            #pragma unroll
            for (int j = 0; j < 2; ++j)
                bf[j] = __builtin_bit_cast(bf16x8,
                    *(const s16x8*)(&Bls[cur][(wn * 32 + j * 16 + l16) * 64 + csw8]));
            #pragma unroll
            for (int i = 0; i < 4; ++i)
                #pragma unroll
                for (int j = 0; j < 2; ++j)
                    acc[i][j] = __builtin_amdgcn_mfma_f32_16x16x32_bf16(
                        af[i], bf[j], acc[i][j], 0, 0, 0);
        }
        if (ks < 3)
            __builtin_amdgcn_s_barrier(); // reads of cur done before re-stage
    }

    // epilogue 1: H write (C/D col=l16, row=quad*4+reg)
    int gcol0 = bc * 128 + wn * 32;
    int t   = gcol0 >> 8;
    int ch0 = gcol0 & 255;
    int c32 = bc * 4 + wn;                       // 0..23 (type = c32>>3)
    u16* Ht = H + (size_t)t * GAT_N * GAT_D;
    int rowb = br * 128 + wm * 64 + quad * 4;
    #pragma unroll
    for (int i = 0; i < 4; ++i) {
        #pragma unroll
        for (int j = 0; j < 2; ++j) {
            int ch = ch0 + j * 16 + l16;
            #pragma unroll
            for (int r = 0; r < 4; ++r) {
                int row = rowb + i * 16 + r;
                if (row < GAT_N) Ht[(size_t)row * GAT_D + ch] = f2bf(acc[i][j][r]);
            }
        }
    }

    // epilogue 2: attn dot partials (deterministic, no atomics, no pre-zero)
    float asv[2], adv[2];
    #pragma unroll
    for (int j = 0; j < 2; ++j) {
        int ch = ch0 + j * 16 + l16;
        asv[j] = as_in[t * GAT_D + ch];
        adv[j] = ad_in[t * GAT_D + ch];
    }
    #pragma unroll
    for (int i = 0; i < 4; ++i) {
        float ps[4] = {}, pd[4] = {};
        #pragma unroll
        for (int j = 0; j < 2; ++j) {
            f32x4 a = acc[i][j];
            #pragma unroll
            for (int r = 0; r < 4; ++r) {
                ps[r] += a[r] * asv[j];
                pd[r] += a[r] * adv[j];
            }
        }
        #pragma unroll
        for (int d = 1; d < 16; d <<= 1) {
            #pragma unroll
            for (int r = 0; r < 4; ++r) {
                ps[r] += __shfl_xor(ps[r], d);
                pd[r] += __shfl_xor(pd[r], d);
            }
        }
        if (l16 == 0) {
            int row = rowb + i * 16;
            #pragma unroll
            for (int r = 0; r < 4; ++r) {
                if (row + r < GAT_N) {
                    part_src[(size_t)c32 * GAT_N + row + r] = ps[r];
                    part_dst[(size_t)c32 * GAT_N + row + r] = pd[r];
                }
            }
        }
    }
}

// ---- reduce 8 col-chunk partials -> a_src/a_dst[t*N+n] (coalesced) --------
__global__ void gat_sum(const float* __restrict__ part_src,
                        const float* __restrict__ part_dst,
                        float* __restrict__ a_src, float* __restrict__ a_dst)
{
    int idx = blockIdx.x * 256 + threadIdx.x;        // [0, 3N)
    if (idx >= GAT_B) return;
    int t = idx / GAT_N;
    int n = idx - t * GAT_N;
    const float* ps = part_src + (size_t)8 * t * GAT_N;
    const float* pd = part_dst + (size_t)8 * t * GAT_N;
    float s = 0.f, d = 0.f;
    #pragma unroll
    for (int c = 0; c < 8; ++c) {
        s += ps[(size_t)c * GAT_N + n];
        d += pd[(size_t)c * GAT_N + n];
    }
    a_src[idx] = s;
    a_dst[idx] = d;
}

// ================= gather: register softmax (shfl) + flat FMA loop ==========
// 4 waves per 256-thread block, each wave owns one dst node (r2: 1-wave
// blocks hit the per-CU workgroup-slot cap -> Occ 72%, latency-bound at
// 3.7 TB/s; 4-wave blocks lift resident-wave count, no LDS/sync needed).
// lane j owns edge j (dtot <= 64: Poisson(15), P(>64) ~ 1e-21).
// Max-subtraction dropped (scores are O(0.5); exp is exact identity).
__global__ __launch_bounds__(256) void gat_gather(
    const u32* __restrict__ pos2, const u32* __restrict__ degp,
    const int* __restrict__ psrc, const float* __restrict__ a_src,
    const float* __restrict__ a_dst, const u16* __restrict__ Hfb,
    const float* __restrict__ bias3, const float* __restrict__ Wh,
    const float* __restrict__ bh, int layer, u16* __restrict__ x2b,
    float* __restrict__ out)
{
    int n = blockIdx.x * 4 + (threadIdx.x >> 6);
    if (n >= GAT_N) return;
    int lane = threadIdx.x & 63;
    int half = lane >> 5, l32 = lane & 31;

    u32 o0 = pos2[n];
    u32 dp = degp[n];
    int d0 = dp & 255, d1 = (dp >> 8) & 255;
    int dtot = d0 + d1 + ((dp >> 16) & 255);
    if (dtot > 64) dtot = 64;                        // unreachable

    // lane j: edge j's score + exp
    int  j     = lane;
    bool valid = j < dtot;
    int  tj    = (j >= d0) + (j >= d0 + d1);
    int  rs    = valid ? psrc[o0 + j] : 0;
    float as   = a_src[rs];                          // 600 KB array: L2-hit
    float adn  = a_dst[tj * GAT_N + n];
    float e = as + adn;
    e = (e > 0.f) ? e : GAT_SLOPE * e;
    float ex = valid ? __expf(e) : 0.f;

    // segmented (per-type) sums via 3 interleaved wave reductions
    float s0 = (tj == 0) ? ex : 0.f;
    float s1 = (tj == 1) ? ex : 0.f;
    float s2 = (tj == 2) ? ex : 0.f;
    #pragma unroll
    for (int d = 1; d < 64; d <<= 1) {
        s0 += __shfl_xor(s0, d);
        s1 += __shfl_xor(s1, d);
        s2 += __shfl_xor(s2, d);
    }
    float den = (tj == 0) ? s0 : ((tj == 1) ? s1 : s2);
    float alv = valid ? ex / den : 0.f;              // this lane's alpha

    // flat FMA loop: 8 edges/iter (4 per half-wave, 4x16B in flight/lane)
    float r[8] = {};
    const u16* Hb = Hfb + l32 * 8;
    for (int k0 = 0; k0 < dtot; k0 += 8) {
        float al[4]; u32x4 w[4];
        #pragma unroll
        for (int u = 0; u < 4; ++u) {
            int j2 = k0 + 2 * u + half;
            float a = __shfl(alv, j2);
            int   rv = __shfl(rs, j2);
            bool  v = j2 < dtot;
            al[u] = v ? a : 0.f;
            rv = v ? rv : 0;
            w[u] = *(const u32x4*)(Hb + (size_t)rv * GAT_D);
        }
        #pragma unroll
        for (int u = 0; u < 4; ++u) {
            r[0] += al[u] * lo16(w[u].x); r[1] += al[u] * hi16(w[u].x);
            r[2] += al[u] * lo16(w[u].y); r[3] += al[u] * hi16(w[u].y);
            r[4] += al[u] * lo16(w[u].z); r[5] += al[u] * hi16(w[u].z);
            r[6] += al[u] * lo16(w[u].w); r[7] += al[u] * hi16(w[u].w);
        }
    }
    #pragma unroll
    for (int i = 0; i < 8; ++i) r[i] += __shfl_xor(r[i], 32);

    int c0 = l32 * 8;
    const float* b3 = bias3 + layer * GAT_D;
    float v[8];
    #pragma unroll
    for (int i = 0; i < 8; ++i) v[i] = fmaxf(r[i] + b3[c0 + i], 0.f);

    if (layer == 0) {
        if (half == 0) {
            u16 pk[8];
            #pragma unroll
            for (int i = 0; i < 8; ++i) pk[i] = f2bf(v[i]);
            *(s16x8*)(x2b + (size_t)n * GAT_D + c0) = *(s16x8*)pk;
        }
    } else {
        float wsum = 0.f;
        #pragma unroll
        for (int i = 0; i < 8; ++i) wsum += v[i] * Wh[c0 + i];
        #pragma unroll
        for (int d2 = 1; d2 < 32; d2 <<= 1) wsum += __shfl_xor(wsum, d2);
        if (lane == 0) out[n] = 1.0f / (1.0f + __expf(-(wsum + bh[0])));
    }
}

// retain harness-expected symbol
__global__ void PyGTypeSpecificGAT_80075370266775_kernel() {}

extern "C" void kernel_launch(void* const* d_in, const int* in_sizes, int n_in,
                              void* d_out, int out_size, void* d_ws, size_t ws_size,
                              hipStream_t stream)
{
    (void)in_sizes; (void)n_in; (void)out_size; (void)ws_size;
    const float* z   = (const float*)d_in[0];
    const int*   ei  = (const int*)d_in[1];
    const float* W1  = (const float*)d_in[2];
    const float* as1 = (const float*)d_in[3];
    const float* ad1 = (const float*)d_in[4];
    const float* b1  = (const float*)d_in[5];
    const float* W2  = (const float*)d_in[6];
    const float* as2 = (const float*)d_in[7];
    const float* ad2 = (const float*)d_in[8];
    const float* b2  = (const float*)d_in[9];
    const float* Wh  = (const float*)d_in[10];
    const float* bh  = (const float*)d_in[11];
    float* out = (float*)d_out;

    // ---- workspace (~147 MB; >=156 MB proven). zb/x2b must not be last
    // (gemm staging over-reads <=24 KB past row 50000).
    char* p = (char*)d_ws;
    u16*  Hfb  = (u16*)p;  p += (size_t)GAT_T * GAT_N * GAT_D * 2;  // 76.8 MB
    u16*  x2b  = (u16*)p;  p += (size_t)GAT_N * GAT_D * 2;          // 25.6 MB
    u16*  zb   = (u16*)p;  p += (size_t)GAT_N * GAT_D * 2;          // 25.6 MB
    float* part_src = (float*)p; p += (size_t)24 * GAT_N * 4;       // 4.8 MB
    float* part_dst = (float*)p; p += (size_t)24 * GAT_N * 4;       // 4.8 MB
    float* a_src = (float*)p; p += (size_t)GAT_B * 4;               // 0.6 MB
    float* a_dst = (float*)p; p += (size_t)GAT_B * 4;               // 0.6 MB
    u32*  cnt  = (u32*)p;  p += (size_t)GAT_B * 4;
    u32*  cur  = (u32*)p;  p += (size_t)GAT_B * 4;
    u32*  pos2 = (u32*)p;  p += (size_t)GAT_N * 4;
    u32*  degp = (u32*)p;  p += (size_t)GAT_N * 4;
    u32*  total = (u32*)p; p += 256;
    int*  psrc = (int*)p;  p += (size_t)GAT_TOTE * 4;               // 3 MB
    u16*  WT1b = (u16*)p;  p += (size_t)GAT_COLS * GAT_D * 2;
    u16*  WT2b = (u16*)p;  p += (size_t)GAT_COLS * GAT_D * 2;
    float* bias3 = (float*)p; p += 2 * GAT_D * 4;

    const int NODE_BLKS = (GAT_N + 255) / 256;              // 196
    const int EDGE_BLKS = (GAT_TOTE + 255) / 256;           // 2930
    const int BUCK_BLKS = (GAT_B + 255) / 256;              // 586
    const int PREP_BLKS = (GAT_N * GAT_D / 4 + 255) / 256;  // 12500

    gat_zero<<<BUCK_BLKS, 256, 0, stream>>>(cnt, total);
    gat_prep<<<PREP_BLKS, 256, 0, stream>>>(W1, W2, z, b1, b2, ei,
                                            WT1b, WT2b, zb, cnt, bias3);
    gat_alloc<<<NODE_BLKS, 256, 0, stream>>>(cnt, pos2, degp, cur, total);
    gat_scatter<<<EDGE_BLKS, 256, 0, stream>>>(ei, cur, psrc);

    // 49 slab-groups of 8 x 6 col tiles = 2352 blocks (6 tail blocks idle)
    const int GEMM_BLKS = 49 * 48;
    const int GATH_BLKS = GAT_N / 4;                        // 12500

    for (int layer = 0; layer < 2; ++layer) {
        const u16*   A   = (layer == 0) ? zb   : x2b;
        const u16*   WTb = (layer == 0) ? WT1b : WT2b;
        const float* as_ = (layer == 0) ? as1  : as2;
        const float* ad_ = (layer == 0) ? ad1  : ad2;

        gat_gemm<<<GEMM_BLKS, 512, 0, stream>>>(A, WTb, Hfb, as_, ad_,
                                                part_src, part_dst);
        gat_sum<<<BUCK_BLKS, 256, 0, stream>>>(part_src, part_dst,
                                               a_src, a_dst);
        gat_gather<<<GATH_BLKS, 256, 0, stream>>>(pos2, degp, psrc,
                                                  a_src, a_dst, Hfb, bias3,
                                                  Wh, bh, layer, x2b, out);
    }
}

// Round 5
// 416.759 us; speedup vs baseline: 1.0451x; 1.0451x over previous
//
#include <hip/hip_runtime.h>

#define GAT_N 50000
#define GAT_D 256
#define GAT_T 3
#define GAT_E 250000
#define GAT_B (GAT_T*GAT_N)      // 150000 (node,type) buckets
#define GAT_TOTE (GAT_T*GAT_E)   // 750000 edges total
#define GAT_COLS (GAT_T*GAT_D)   // 768 fused output columns
#define GAT_SLOPE 0.2f

typedef unsigned short u16;
typedef unsigned int u32;
typedef __attribute__((ext_vector_type(8))) short s16x8;     // raw bf16 storage
typedef __attribute__((ext_vector_type(8))) __bf16 bf16x8;   // MFMA operand
typedef __attribute__((ext_vector_type(4))) float f32x4;
typedef __attribute__((ext_vector_type(4))) u32 u32x4;

__device__ __forceinline__ u16 f2bf(float f) {
    u32 x = __builtin_bit_cast(u32, f);
    u32 r = (x + 0x7fffu + ((x >> 16) & 1u)) >> 16;   // RNE
    return (u16)r;
}
__device__ __forceinline__ float lo16(u32 w) {
    return __builtin_bit_cast(float, w << 16);
}
__device__ __forceinline__ float hi16(u32 w) {
    return __builtin_bit_cast(float, w & 0xffff0000u);
}

// ---- DPP butterfly adds (VALU pipe, NOT ds_swizzle/LDS pipe) --------------
// xor1 = quad_perm(1,0,3,2)=0xB1 (exact), xor2 = quad_perm(2,3,0,1)=0x4E
// (exact), row_half_mirror(0x141) = ^7 == ^4 after 4-lane uniformity,
// row_mirror(0x140) = ^15 == ^8 after 8-lane uniformity. Same masks, same
// add order as the old __shfl_xor butterfly -> bit-identical results.
template<int CTRL>
__device__ __forceinline__ float dppadd(float x) {
    int y = __builtin_amdgcn_update_dpp(0, __builtin_bit_cast(int, x),
                                        CTRL, 0xf, 0xf, true);
    return x + __builtin_bit_cast(float, y);
}
__device__ __forceinline__ float sum16(float x) {   // reduce within 16 lanes
    x = dppadd<0xB1>(x);
    x = dppadd<0x4E>(x);
    x = dppadd<0x141>(x);
    x = dppadd<0x140>(x);
    return x;
}

// ---- fused prep: W1/W2 -> bf16 transposed, z -> bf16, cnt/total -> 0, bias3
__global__ void gat_prep(const float* __restrict__ W1, const float* __restrict__ W2,
                         const float* __restrict__ z, const float* __restrict__ b1,
                         const float* __restrict__ b2, u16* __restrict__ WT1b,
                         u16* __restrict__ WT2b, u16* __restrict__ zb,
                         u32* __restrict__ cnt, u32* __restrict__ total,
                         float* __restrict__ bias3)
{
    int idx = blockIdx.x * 256 + threadIdx.x;
    if (idx == 0) *total = 0u;
    if (idx < GAT_T * GAT_D * GAT_D) {               // 196608
        int t = idx >> 16, r = idx & 65535;
        int d = r >> 8, h = r & 255;
        WT1b[t * 65536 + h * 256 + d] = f2bf(W1[idx]);
        WT2b[t * 65536 + h * 256 + d] = f2bf(W2[idx]);
    }
    if (idx < GAT_B) cnt[idx] = 0u;
    if (idx < 2 * GAT_D) {
        const float* bb = (idx < GAT_D) ? b1 : b2;
        int c = idx & 255;
        bias3[idx] = bb[c] + bb[GAT_D + c] + bb[2 * GAT_D + c];
    }
    if (idx < GAT_N * GAT_D / 4) {
        f32x4 v = ((const f32x4*)z)[idx];
        ushort4 pk;
        pk.x = f2bf(v.x); pk.y = f2bf(v.y); pk.z = f2bf(v.z); pk.w = f2bf(v.w);
        ((ushort4*)zb)[idx] = pk;
    }
}

// ================= CSR build: per-node contiguous triples ===================
__global__ void gat_hist(const int* __restrict__ ei, u32* __restrict__ cnt) {
    int idx = blockIdx.x * 256 + threadIdx.x;
    if (idx >= GAT_TOTE) return;
    int t = idx / GAT_E;
    int e = idx - t * GAT_E;
    int dst = ei[t * 2 * GAT_E + GAT_E + e];
    atomicAdd(&cnt[dst * GAT_T + t], 1u);
}

// one thread per NODE: contiguous slab for its 3 type-segments
__global__ void gat_alloc(const u32* __restrict__ cnt, u32* __restrict__ pos2,
                          u32* __restrict__ degp, u32* __restrict__ cur,
                          u32* __restrict__ total)
{
    int n = blockIdx.x * 256 + threadIdx.x;
    if (n >= GAT_N) return;
    u32 c0 = cnt[3 * n], c1 = cnt[3 * n + 1], c2 = cnt[3 * n + 2];
    u32 p = atomicAdd(total, c0 + c1 + c2);
    pos2[n] = p;
    degp[n] = c0 | (c1 << 8) | (c2 << 16);
    cur[3 * n]     = p;
    cur[3 * n + 1] = p + c0;
    cur[3 * n + 2] = p + c0 + c1;
}

// psrc stores ABSOLUTE H row (t*N+src)
__global__ void gat_scatter(const int* __restrict__ ei, u32* __restrict__ cur,
                            int* __restrict__ psrc)
{
    int idx = blockIdx.x * 256 + threadIdx.x;
    if (idx >= GAT_TOTE) return;
    int t = idx / GAT_E;
    int e = idx - t * GAT_E;
    int src = ei[t * 2 * GAT_E + e];
    int dst = ei[t * 2 * GAT_E + GAT_E + e];
    u32 slot = atomicAdd(&cur[dst * GAT_T + t], 1u);
    psrc[slot] = t * GAT_N + src;
}

// ================= LDS-staged MFMA GEMM (XOR-swizzled) + partial attn dots ==
// Swizzle: LDS[row][chunk j] = G[row][j ^ (row&7)] via permuted per-lane
// global source addr (keeps global_load_lds wave-uniform dest + coalescing).
// Grid swizzle: lin = (r/8)*48 + c*8 + (r%8) -> col siblings share an XCD.
// Dbuf K-loop, counted vmcnt (r3). 512-thread / 8-wave blocks (r4).
//
// r5: epilogue-2 reduction moved from __shfl_xor (ds_swizzle, LDS pipe) to
// DPP adds (VALU pipe). r4 post-mortem: no visible pipe busy (Mfma 12%,
// VALU 28%, hbm 19%, conflicts 0) -> LDS-pipe issue-bound; epi2's 128
// swizzles/thread were ~half the per-block LDS cycles.
__global__ __launch_bounds__(512, 4) void gat_gemm(
    const u16* __restrict__ A, const u16* __restrict__ WTb,
    u16* __restrict__ H, const float* __restrict__ as_in,
    const float* __restrict__ ad_in, float* __restrict__ part_src,
    float* __restrict__ part_dst)
{
    // decode XCD-grouped swizzle
    int lin = blockIdx.x;
    int g   = lin / 48;
    int rem = lin - g * 48;
    int bc  = rem >> 3;                 // col tile 0..5
    int br  = (g << 3) + (rem & 7);     // row slab 0..390
    if (br >= 391) return;

    __shared__ u16 Als[2][128 * 64];   // 2 x 16 KB
    __shared__ u16 Bls[2][128 * 64];   // 2 x 16 KB
    int tid  = threadIdx.x;
    int wave = tid >> 6, lane = tid & 63;
    int quad = lane >> 4, l16 = lane & 15;
    int wm = wave & 1, wn = wave >> 1;       // wm: row half, wn: col quarter
    int lrow = lane >> 3;                    // 0..7
    int swz  = ((lane & 7) ^ lrow) * 8;      // swizzled k-offset (u16)

    size_t arow0 = (size_t)br * 128;
    size_t brow0 = (size_t)bc * 128;

    // stage K-chunk ks into buffer buf: 4 global_load_lds per wave
    // (2 x 8-row groups x {A,B}); wave w covers rows [w*16, w*16+16).
    auto STAGE = [&](int buf, int ks) {
        int k0 = ks * 64;
        #pragma unroll
        for (int r = 0; r < 2; ++r) {
            int srow = wave * 16 + r * 8 + lrow;
            const u16* gA = A   + (arow0 + srow) * GAT_D + k0 + swz;
            const u16* gB = WTb + (brow0 + srow) * GAT_D + k0 + swz;
            u16* lA = &Als[buf][wave * 1024 + r * 512];   // wave-uniform dest
            u16* lB = &Bls[buf][wave * 1024 + r * 512];
#if defined(__has_builtin) && __has_builtin(__builtin_amdgcn_global_load_lds)
            __builtin_amdgcn_global_load_lds(
                (const __attribute__((address_space(1))) void*)gA,
                (__attribute__((address_space(3))) void*)lA, 16, 0, 0);
            __builtin_amdgcn_global_load_lds(
                (const __attribute__((address_space(1))) void*)gB,
                (__attribute__((address_space(3))) void*)lB, 16, 0, 0);
#else
            *(s16x8*)(lA + lane * 8) = *(const s16x8*)gA;
            *(s16x8*)(lB + lane * 8) = *(const s16x8*)gB;
#endif
        }
    };

    f32x4 acc[4][2] = {};

    STAGE(0, 0);
    #pragma unroll
    for (int ks = 0; ks < 4; ++ks) {
        int cur = ks & 1;
        if (ks < 3) {
            STAGE(cur ^ 1, ks + 1);
            // wait for buf[cur]'s 4 loads; buf[cur^1]'s 4 stay in flight
            asm volatile("s_waitcnt vmcnt(4)" ::: "memory");
        } else {
            asm volatile("s_waitcnt vmcnt(0)" ::: "memory");
        }
        __builtin_amdgcn_s_barrier();     // all waves' stage of cur complete

        #pragma unroll
        for (int kk = 0; kk < 2; ++kk) {
            int csw8 = ((kk * 4 + quad) ^ (l16 & 7)) * 8;   // row&7 == l16&7
            bf16x8 af[4], bf[2];
            #pragma unroll
            for (int i = 0; i < 4; ++i)
                af[i] = __builtin_bit_cast(bf16x8,
                    *(const s16x8*)(&Als[cur][(wm * 64 + i * 16 + l16) * 64 + csw8]));
            #pragma unroll
            for (int j = 0; j < 2; ++j)
                bf[j] = __builtin_bit_cast(bf16x8,
                    *(const s16x8*)(&Bls[cur][(wn * 32 + j * 16 + l16) * 64 + csw8]));
            #pragma unroll
            for (int i = 0; i < 4; ++i)
                #pragma unroll
                for (int j = 0; j < 2; ++j)
                    acc[i][j] = __builtin_amdgcn_mfma_f32_16x16x32_bf16(
                        af[i], bf[j], acc[i][j], 0, 0, 0);
        }
        if (ks < 3)
            __builtin_amdgcn_s_barrier(); // reads of cur done before re-stage
    }

    // epilogue 1: H write (C/D col=l16, row=quad*4+reg)
    int gcol0 = bc * 128 + wn * 32;
    int t   = gcol0 >> 8;
    int ch0 = gcol0 & 255;
    int c32 = bc * 4 + wn;                       // 0..23 (type = c32>>3)
    u16* Ht = H + (size_t)t * GAT_N * GAT_D;
    int rowb = br * 128 + wm * 64 + quad * 4;
    #pragma unroll
    for (int i = 0; i < 4; ++i) {
        #pragma unroll
        for (int j = 0; j < 2; ++j) {
            int ch = ch0 + j * 16 + l16;
            #pragma unroll
            for (int r = 0; r < 4; ++r) {
                int row = rowb + i * 16 + r;
                if (row < GAT_N) Ht[(size_t)row * GAT_D + ch] = f2bf(acc[i][j][r]);
            }
        }
    }

    // epilogue 2: attn dot partials (deterministic, no atomics, no pre-zero)
    // r5: reduction over the 16 l16 lanes via DPP (VALU), not shfl (LDS).
    float asv[2], adv[2];
    #pragma unroll
    for (int j = 0; j < 2; ++j) {
        int ch = ch0 + j * 16 + l16;
        asv[j] = as_in[t * GAT_D + ch];
        adv[j] = ad_in[t * GAT_D + ch];
    }
    #pragma unroll
    for (int i = 0; i < 4; ++i) {
        float ps[4] = {}, pd[4] = {};
        #pragma unroll
        for (int j = 0; j < 2; ++j) {
            f32x4 a = acc[i][j];
            #pragma unroll
            for (int r = 0; r < 4; ++r) {
                ps[r] += a[r] * asv[j];
                pd[r] += a[r] * adv[j];
            }
        }
        #pragma unroll
        for (int r = 0; r < 4; ++r) {
            ps[r] = sum16(ps[r]);
            pd[r] = sum16(pd[r]);
        }
        if (l16 == 0) {
            int row = rowb + i * 16;
            #pragma unroll
            for (int r = 0; r < 4; ++r) {
                if (row + r < GAT_N) {
                    part_src[(size_t)c32 * GAT_N + row + r] = ps[r];
                    part_dst[(size_t)c32 * GAT_N + row + r] = pd[r];
                }
            }
        }
    }
}

// ---- reduce 8 col-chunk partials -> a_src/a_dst[t*N+n] (coalesced) --------
__global__ void gat_sum(const float* __restrict__ part_src,
                        const float* __restrict__ part_dst,
                        float* __restrict__ a_src, float* __restrict__ a_dst)
{
    int idx = blockIdx.x * 256 + threadIdx.x;        // [0, 3N)
    if (idx >= GAT_B) return;
    int t = idx / GAT_N;
    int n = idx - t * GAT_N;
    const float* ps = part_src + (size_t)8 * t * GAT_N;
    const float* pd = part_dst + (size_t)8 * t * GAT_N;
    float s = 0.f, d = 0.f;
    #pragma unroll
    for (int c = 0; c < 8; ++c) {
        s += ps[(size_t)c * GAT_N + n];
        d += pd[(size_t)c * GAT_N + n];
    }
    a_src[idx] = s;
    a_dst[idx] = d;
}

// ================= gather: register softmax (shfl) + flat FMA loop ==========
// 4 waves per 256-thread block, each wave owns one dst node. lane j owns
// edge j (dtot <= 64: Poisson(15), P(>64) ~ 1e-21). Max-subtraction dropped
// (scores O(0.5); exp identity). r5: 16 edges/iter (8 x16B in flight/lane,
// avg degree 15 -> one fully-pipelined iteration for most nodes); softmax
// butterfly steps 1,2,4,8 via DPP.
__global__ __launch_bounds__(256) void gat_gather(
    const u32* __restrict__ pos2, const u32* __restrict__ degp,
    const int* __restrict__ psrc, const float* __restrict__ a_src,
    const float* __restrict__ a_dst, const u16* __restrict__ Hfb,
    const float* __restrict__ bias3, const float* __restrict__ Wh,
    const float* __restrict__ bh, int layer, u16* __restrict__ x2b,
    float* __restrict__ out)
{
    int n = blockIdx.x * 4 + (threadIdx.x >> 6);
    if (n >= GAT_N) return;
    int lane = threadIdx.x & 63;
    int half = lane >> 5, l32 = lane & 31;

    u32 o0 = pos2[n];
    u32 dp = degp[n];
    int d0 = dp & 255, d1 = (dp >> 8) & 255;
    int dtot = d0 + d1 + ((dp >> 16) & 255);
    if (dtot > 64) dtot = 64;                        // unreachable

    // lane j: edge j's score + exp
    int  j     = lane;
    bool valid = j < dtot;
    int  tj    = (j >= d0) + (j >= d0 + d1);
    int  rs    = valid ? psrc[o0 + j] : 0;
    float as   = a_src[rs];                          // 600 KB array: L2-hit
    float adn  = a_dst[tj * GAT_N + n];
    float e = as + adn;
    e = (e > 0.f) ? e : GAT_SLOPE * e;
    float ex = valid ? __expf(e) : 0.f;

    // segmented (per-type) sums via 3 interleaved wave reductions
    // (d=1,2,4,8 on VALU via DPP; d=16,32 cross-row via shfl)
    float s0 = (tj == 0) ? ex : 0.f;
    float s1 = (tj == 1) ? ex : 0.f;
    float s2 = (tj == 2) ? ex : 0.f;
    s0 = sum16(s0); s1 = sum16(s1); s2 = sum16(s2);
    #pragma unroll
    for (int d = 16; d < 64; d <<= 1) {
        s0 += __shfl_xor(s0, d);
        s1 += __shfl_xor(s1, d);
        s2 += __shfl_xor(s2, d);
    }
    float den = (tj == 0) ? s0 : ((tj == 1) ? s1 : s2);
    float alv = valid ? ex / den : 0.f;              // this lane's alpha

    // flat FMA loop: 16 edges/iter (8 per half-wave, 8x16B in flight/lane)
    float r[8] = {};
    const u16* Hb = Hfb + l32 * 8;
    for (int k0 = 0; k0 < dtot; k0 += 16) {
        float al[8]; u32x4 w[8];
        #pragma unroll
        for (int u = 0; u < 8; ++u) {
            int j2 = k0 + 2 * u + half;              // <= 63 always
            float a = __shfl(alv, j2);
            int   rv = __shfl(rs, j2);
            bool  v = j2 < dtot;
            al[u] = v ? a : 0.f;
            rv = v ? rv : 0;
            w[u] = *(const u32x4*)(Hb + (size_t)rv * GAT_D);
        }
        #pragma unroll
        for (int u = 0; u < 8; ++u) {
            r[0] += al[u] * lo16(w[u].x); r[1] += al[u] * hi16(w[u].x);
            r[2] += al[u] * lo16(w[u].y); r[3] += al[u] * hi16(w[u].y);
            r[4] += al[u] * lo16(w[u].z); r[5] += al[u] * hi16(w[u].z);
            r[6] += al[u] * lo16(w[u].w); r[7] += al[u] * hi16(w[u].w);
        }
    }
    #pragma unroll
    for (int i = 0; i < 8; ++i) r[i] += __shfl_xor(r[i], 32);

    int c0 = l32 * 8;
    const float* b3 = bias3 + layer * GAT_D;
    float v[8];
    #pragma unroll
    for (int i = 0; i < 8; ++i) v[i] = fmaxf(r[i] + b3[c0 + i], 0.f);

    if (layer == 0) {
        if (half == 0) {
            u16 pk[8];
            #pragma unroll
            for (int i = 0; i < 8; ++i) pk[i] = f2bf(v[i]);
            *(s16x8*)(x2b + (size_t)n * GAT_D + c0) = *(s16x8*)pk;
        }
    } else {
        float wsum = 0.f;
        #pragma unroll
        for (int i = 0; i < 8; ++i) wsum += v[i] * Wh[c0 + i];
        #pragma unroll
        for (int d2 = 1; d2 < 32; d2 <<= 1) wsum += __shfl_xor(wsum, d2);
        if (lane == 0) out[n] = 1.0f / (1.0f + __expf(-(wsum + bh[0])));
    }
}

// retain harness-expected symbol
__global__ void PyGTypeSpecificGAT_80075370266775_kernel() {}

extern "C" void kernel_launch(void* const* d_in, const int* in_sizes, int n_in,
                              void* d_out, int out_size, void* d_ws, size_t ws_size,
                              hipStream_t stream)
{
    (void)in_sizes; (void)n_in; (void)out_size; (void)ws_size;
    const float* z   = (const float*)d_in[0];
    const int*   ei  = (const int*)d_in[1];
    const float* W1  = (const float*)d_in[2];
    const float* as1 = (const float*)d_in[3];
    const float* ad1 = (const float*)d_in[4];
    const float* b1  = (const float*)d_in[5];
    const float* W2  = (const float*)d_in[6];
    const float* as2 = (const float*)d_in[7];
    const float* ad2 = (const float*)d_in[8];
    const float* b2  = (const float*)d_in[9];
    const float* Wh  = (const float*)d_in[10];
    const float* bh  = (const float*)d_in[11];
    float* out = (float*)d_out;

    // ---- workspace (~147 MB; >=156 MB proven). zb/x2b must not be last
    // (gemm staging over-reads <=24 KB past row 50000).
    char* p = (char*)d_ws;
    u16*  Hfb  = (u16*)p;  p += (size_t)GAT_T * GAT_N * GAT_D * 2;  // 76.8 MB
    u16*  x2b  = (u16*)p;  p += (size_t)GAT_N * GAT_D * 2;          // 25.6 MB
    u16*  zb   = (u16*)p;  p += (size_t)GAT_N * GAT_D * 2;          // 25.6 MB
    float* part_src = (float*)p; p += (size_t)24 * GAT_N * 4;       // 4.8 MB
    float* part_dst = (float*)p; p += (size_t)24 * GAT_N * 4;       // 4.8 MB
    float* a_src = (float*)p; p += (size_t)GAT_B * 4;               // 0.6 MB
    float* a_dst = (float*)p; p += (size_t)GAT_B * 4;               // 0.6 MB
    u32*  cnt  = (u32*)p;  p += (size_t)GAT_B * 4;
    u32*  cur  = (u32*)p;  p += (size_t)GAT_B * 4;
    u32*  pos2 = (u32*)p;  p += (size_t)GAT_N * 4;
    u32*  degp = (u32*)p;  p += (size_t)GAT_N * 4;
    u32*  total = (u32*)p; p += 256;
    int*  psrc = (int*)p;  p += (size_t)GAT_TOTE * 4;               // 3 MB
    u16*  WT1b = (u16*)p;  p += (size_t)GAT_COLS * GAT_D * 2;
    u16*  WT2b = (u16*)p;  p += (size_t)GAT_COLS * GAT_D * 2;
    float* bias3 = (float*)p; p += 2 * GAT_D * 4;

    const int NODE_BLKS = (GAT_N + 255) / 256;              // 196
    const int EDGE_BLKS = (GAT_TOTE + 255) / 256;           // 2930
    const int BUCK_BLKS = (GAT_B + 255) / 256;              // 586
    const int PREP_BLKS = (GAT_N * GAT_D / 4 + 255) / 256;  // 12500

    gat_prep<<<PREP_BLKS, 256, 0, stream>>>(W1, W2, z, b1, b2, WT1b, WT2b,
                                            zb, cnt, total, bias3);
    gat_hist<<<EDGE_BLKS, 256, 0, stream>>>(ei, cnt);
    gat_alloc<<<NODE_BLKS, 256, 0, stream>>>(cnt, pos2, degp, cur, total);
    gat_scatter<<<EDGE_BLKS, 256, 0, stream>>>(ei, cur, psrc);

    // 49 slab-groups of 8 x 6 col tiles = 2352 blocks (6 tail blocks idle)
    const int GEMM_BLKS = 49 * 48;
    const int GATH_BLKS = GAT_N / 4;                        // 12500

    for (int layer = 0; layer < 2; ++layer) {
        const u16*   A   = (layer == 0) ? zb   : x2b;
        const u16*   WTb = (layer == 0) ? WT1b : WT2b;
        const float* as_ = (layer == 0) ? as1  : as2;
        const float* ad_ = (layer == 0) ? ad1  : ad2;

        gat_gemm<<<GEMM_BLKS, 512, 0, stream>>>(A, WTb, Hfb, as_, ad_,
                                                part_src, part_dst);
        gat_sum<<<BUCK_BLKS, 256, 0, stream>>>(part_src, part_dst,
                                               a_src, a_dst);
        gat_gather<<<GATH_BLKS, 256, 0, stream>>>(pos2, degp, psrc,
                                                  a_src, a_dst, Hfb, bias3,
                                                  Wh, bh, layer, x2b, out);
    }
}

// Round 6
// 409.890 us; speedup vs baseline: 1.0626x; 1.0168x over previous
//
#include <hip/hip_runtime.h>

#define GAT_N 50000
#define GAT_D 256
#define GAT_T 3
#define GAT_E 250000
#define GAT_B (GAT_T*GAT_N)      // 150000 (node,type) buckets
#define GAT_TOTE (GAT_T*GAT_E)   // 750000 edges total
#define GAT_COLS (GAT_T*GAT_D)   // 768 fused output columns
#define GAT_SLOPE 0.2f

typedef unsigned short u16;
typedef unsigned int u32;
typedef __attribute__((ext_vector_type(8))) short s16x8;     // raw bf16 storage
typedef __attribute__((ext_vector_type(8))) __bf16 bf16x8;   // MFMA operand
typedef __attribute__((ext_vector_type(4))) float f32x4;
typedef __attribute__((ext_vector_type(2))) u32 u32x2;

__device__ __forceinline__ u16 f2bf(float f) {
    u32 x = __builtin_bit_cast(u32, f);
    u32 r = (x + 0x7fffu + ((x >> 16) & 1u)) >> 16;   // RNE
    return (u16)r;
}
__device__ __forceinline__ float lo16(u32 w) {
    return __builtin_bit_cast(float, w << 16);
}
__device__ __forceinline__ float hi16(u32 w) {
    return __builtin_bit_cast(float, w & 0xffff0000u);
}

// ---- DPP butterfly adds (VALU pipe, NOT ds_swizzle/LDS pipe) --------------
// xor1 = quad_perm(1,0,3,2)=0xB1 (exact), xor2 = quad_perm(2,3,0,1)=0x4E
// (exact), row_half_mirror(0x141) = ^7 == ^4 after 4-lane uniformity,
// row_mirror(0x140) = ^15 == ^8 after 8-lane uniformity. Same masks, same
// add order as a __shfl_xor butterfly -> bit-identical results.
template<int CTRL>
__device__ __forceinline__ float dppadd(float x) {
    int y = __builtin_amdgcn_update_dpp(0, __builtin_bit_cast(int, x),
                                        CTRL, 0xf, 0xf, true);
    return x + __builtin_bit_cast(float, y);
}
__device__ __forceinline__ float sum16(float x) {   // reduce within 16 lanes
    x = dppadd<0xB1>(x);
    x = dppadd<0x4E>(x);
    x = dppadd<0x141>(x);
    x = dppadd<0x140>(x);
    return x;
}

// ---- fused prep: W1/W2 -> bf16 transposed, z -> bf16, cnt/total -> 0, bias3
__global__ void gat_prep(const float* __restrict__ W1, const float* __restrict__ W2,
                         const float* __restrict__ z, const float* __restrict__ b1,
                         const float* __restrict__ b2, u16* __restrict__ WT1b,
                         u16* __restrict__ WT2b, u16* __restrict__ zb,
                         u32* __restrict__ cnt, u32* __restrict__ total,
                         float* __restrict__ bias3)
{
    int idx = blockIdx.x * 256 + threadIdx.x;
    if (idx == 0) *total = 0u;
    if (idx < GAT_T * GAT_D * GAT_D) {               // 196608
        int t = idx >> 16, r = idx & 65535;
        int d = r >> 8, h = r & 255;
        WT1b[t * 65536 + h * 256 + d] = f2bf(W1[idx]);
        WT2b[t * 65536 + h * 256 + d] = f2bf(W2[idx]);
    }
    if (idx < GAT_B) cnt[idx] = 0u;
    if (idx < 2 * GAT_D) {
        const float* bb = (idx < GAT_D) ? b1 : b2;
        int c = idx & 255;
        bias3[idx] = bb[c] + bb[GAT_D + c] + bb[2 * GAT_D + c];
    }
    if (idx < GAT_N * GAT_D / 4) {
        f32x4 v = ((const f32x4*)z)[idx];
        ushort4 pk;
        pk.x = f2bf(v.x); pk.y = f2bf(v.y); pk.z = f2bf(v.z); pk.w = f2bf(v.w);
        ((ushort4*)zb)[idx] = pk;
    }
}

// ================= CSR build: per-node contiguous triples ===================
__global__ void gat_hist(const int* __restrict__ ei, u32* __restrict__ cnt) {
    int idx = blockIdx.x * 256 + threadIdx.x;
    if (idx >= GAT_TOTE) return;
    int t = idx / GAT_E;
    int e = idx - t * GAT_E;
    int dst = ei[t * 2 * GAT_E + GAT_E + e];
    atomicAdd(&cnt[dst * GAT_T + t], 1u);
}

// one thread per NODE: contiguous slab for its 3 type-segments
__global__ void gat_alloc(const u32* __restrict__ cnt, u32* __restrict__ pos2,
                          u32* __restrict__ degp, u32* __restrict__ cur,
                          u32* __restrict__ total)
{
    int n = blockIdx.x * 256 + threadIdx.x;
    if (n >= GAT_N) return;
    u32 c0 = cnt[3 * n], c1 = cnt[3 * n + 1], c2 = cnt[3 * n + 2];
    u32 p = atomicAdd(total, c0 + c1 + c2);
    pos2[n] = p;
    degp[n] = c0 | (c1 << 8) | (c2 << 16);
    cur[3 * n]     = p;
    cur[3 * n + 1] = p + c0;
    cur[3 * n + 2] = p + c0 + c1;
}

// psrc stores ABSOLUTE H row (t*N+src)
__global__ void gat_scatter(const int* __restrict__ ei, u32* __restrict__ cur,
                            int* __restrict__ psrc)
{
    int idx = blockIdx.x * 256 + threadIdx.x;
    if (idx >= GAT_TOTE) return;
    int t = idx / GAT_E;
    int e = idx - t * GAT_E;
    int src = ei[t * 2 * GAT_E + e];
    int dst = ei[t * 2 * GAT_E + GAT_E + e];
    u32 slot = atomicAdd(&cur[dst * GAT_T + t], 1u);
    psrc[slot] = t * GAT_N + src;
}

// ================= LDS-staged MFMA GEMM (XOR-swizzled) + partial attn dots ==
// Swizzle: LDS[row][chunk j] = G[row][j ^ (row&7)] via permuted per-lane
// global source addr (keeps global_load_lds wave-uniform dest + coalescing).
// Grid swizzle: lin = (r/8)*48 + c*8 + (r%8) -> col siblings share an XCD.
// Dbuf K-loop, counted vmcnt (r3). 512-thread / 8-wave blocks (r4).
// Epilogue-2 reduction via DPP (r5: LDS-pipe relief; gemm 65.5 -> <65).
__global__ __launch_bounds__(512, 4) void gat_gemm(
    const u16* __restrict__ A, const u16* __restrict__ WTb,
    u16* __restrict__ H, const float* __restrict__ as_in,
    const float* __restrict__ ad_in, float* __restrict__ part_src,
    float* __restrict__ part_dst)
{
    // decode XCD-grouped swizzle
    int lin = blockIdx.x;
    int g   = lin / 48;
    int rem = lin - g * 48;
    int bc  = rem >> 3;                 // col tile 0..5
    int br  = (g << 3) + (rem & 7);     // row slab 0..390
    if (br >= 391) return;

    __shared__ u16 Als[2][128 * 64];   // 2 x 16 KB
    __shared__ u16 Bls[2][128 * 64];   // 2 x 16 KB
    int tid  = threadIdx.x;
    int wave = tid >> 6, lane = tid & 63;
    int quad = lane >> 4, l16 = lane & 15;
    int wm = wave & 1, wn = wave >> 1;       // wm: row half, wn: col quarter
    int lrow = lane >> 3;                    // 0..7
    int swz  = ((lane & 7) ^ lrow) * 8;      // swizzled k-offset (u16)

    size_t arow0 = (size_t)br * 128;
    size_t brow0 = (size_t)bc * 128;

    // stage K-chunk ks into buffer buf: 4 global_load_lds per wave
    // (2 x 8-row groups x {A,B}); wave w covers rows [w*16, w*16+16).
    auto STAGE = [&](int buf, int ks) {
        int k0 = ks * 64;
        #pragma unroll
        for (int r = 0; r < 2; ++r) {
            int srow = wave * 16 + r * 8 + lrow;
            const u16* gA = A   + (arow0 + srow) * GAT_D + k0 + swz;
            const u16* gB = WTb + (brow0 + srow) * GAT_D + k0 + swz;
            u16* lA = &Als[buf][wave * 1024 + r * 512];   // wave-uniform dest
            u16* lB = &Bls[buf][wave * 1024 + r * 512];
#if defined(__has_builtin) && __has_builtin(__builtin_amdgcn_global_load_lds)
            __builtin_amdgcn_global_load_lds(
                (const __attribute__((address_space(1))) void*)gA,
                (__attribute__((address_space(3))) void*)lA, 16, 0, 0);
            __builtin_amdgcn_global_load_lds(
                (const __attribute__((address_space(1))) void*)gB,
                (__attribute__((address_space(3))) void*)lB, 16, 0, 0);
#else
            *(s16x8*)(lA + lane * 8) = *(const s16x8*)gA;
            *(s16x8*)(lB + lane * 8) = *(const s16x8*)gB;
#endif
        }
    };

    f32x4 acc[4][2] = {};

    STAGE(0, 0);
    #pragma unroll
    for (int ks = 0; ks < 4; ++ks) {
        int cur = ks & 1;
        if (ks < 3) {
            STAGE(cur ^ 1, ks + 1);
            // wait for buf[cur]'s 4 loads; buf[cur^1]'s 4 stay in flight
            asm volatile("s_waitcnt vmcnt(4)" ::: "memory");
        } else {
            asm volatile("s_waitcnt vmcnt(0)" ::: "memory");
        }
        __builtin_amdgcn_s_barrier();     // all waves' stage of cur complete

        #pragma unroll
        for (int kk = 0; kk < 2; ++kk) {
            int csw8 = ((kk * 4 + quad) ^ (l16 & 7)) * 8;   // row&7 == l16&7
            bf16x8 af[4], bf[2];
            #pragma unroll
            for (int i = 0; i < 4; ++i)
                af[i] = __builtin_bit_cast(bf16x8,
                    *(const s16x8*)(&Als[cur][(wm * 64 + i * 16 + l16) * 64 + csw8]));
            #pragma unroll
            for (int j = 0; j < 2; ++j)
                bf[j] = __builtin_bit_cast(bf16x8,
                    *(const s16x8*)(&Bls[cur][(wn * 32 + j * 16 + l16) * 64 + csw8]));
            #pragma unroll
            for (int i = 0; i < 4; ++i)
                #pragma unroll
                for (int j = 0; j < 2; ++j)
                    acc[i][j] = __builtin_amdgcn_mfma_f32_16x16x32_bf16(
                        af[i], bf[j], acc[i][j], 0, 0, 0);
        }
        if (ks < 3)
            __builtin_amdgcn_s_barrier(); // reads of cur done before re-stage
    }

    // epilogue 1: H write (C/D col=l16, row=quad*4+reg)
    int gcol0 = bc * 128 + wn * 32;
    int t   = gcol0 >> 8;
    int ch0 = gcol0 & 255;
    int c32 = bc * 4 + wn;                       // 0..23 (type = c32>>3)
    u16* Ht = H + (size_t)t * GAT_N * GAT_D;
    int rowb = br * 128 + wm * 64 + quad * 4;
    #pragma unroll
    for (int i = 0; i < 4; ++i) {
        #pragma unroll
        for (int j = 0; j < 2; ++j) {
            int ch = ch0 + j * 16 + l16;
            #pragma unroll
            for (int r = 0; r < 4; ++r) {
                int row = rowb + i * 16 + r;
                if (row < GAT_N) Ht[(size_t)row * GAT_D + ch] = f2bf(acc[i][j][r]);
            }
        }
    }

    // epilogue 2: attn dot partials (deterministic, no atomics, no pre-zero)
    // reduction over the 16 l16 lanes via DPP (VALU), not shfl (LDS).
    float asv[2], adv[2];
    #pragma unroll
    for (int j = 0; j < 2; ++j) {
        int ch = ch0 + j * 16 + l16;
        asv[j] = as_in[t * GAT_D + ch];
        adv[j] = ad_in[t * GAT_D + ch];
    }
    #pragma unroll
    for (int i = 0; i < 4; ++i) {
        float ps[4] = {}, pd[4] = {};
        #pragma unroll
        for (int j = 0; j < 2; ++j) {
            f32x4 a = acc[i][j];
            #pragma unroll
            for (int r = 0; r < 4; ++r) {
                ps[r] += a[r] * asv[j];
                pd[r] += a[r] * adv[j];
            }
        }
        #pragma unroll
        for (int r = 0; r < 4; ++r) {
            ps[r] = sum16(ps[r]);
            pd[r] = sum16(pd[r]);
        }
        if (l16 == 0) {
            int row = rowb + i * 16;
            #pragma unroll
            for (int r = 0; r < 4; ++r) {
                if (row + r < GAT_N) {
                    part_src[(size_t)c32 * GAT_N + row + r] = ps[r];
                    part_dst[(size_t)c32 * GAT_N + row + r] = pd[r];
                }
            }
        }
    }
}

// ---- reduce 8 col-chunk partials -> a_src/a_dst[t*N+n] (coalesced) --------
__global__ void gat_sum(const float* __restrict__ part_src,
                        const float* __restrict__ part_dst,
                        float* __restrict__ a_src, float* __restrict__ a_dst)
{
    int idx = blockIdx.x * 256 + threadIdx.x;        // [0, 3N)
    if (idx >= GAT_B) return;
    int t = idx / GAT_N;
    int n = idx - t * GAT_N;
    const float* ps = part_src + (size_t)8 * t * GAT_N;
    const float* pd = part_dst + (size_t)8 * t * GAT_N;
    float s = 0.f, d = 0.f;
    #pragma unroll
    for (int c = 0; c < 8; ++c) {
        s += ps[(size_t)c * GAT_N + n];
        d += pd[(size_t)c * GAT_N + n];
    }
    a_src[idx] = s;
    a_dst[idx] = d;
}

// ================= gather: wave-per-edge readlane structure =================
// r6 rewrite: one wave per dst node; softmax as before (lane j owns edge j).
// FMA loop restructured: all 64 lanes cooperate on ONE edge per step
// (8 B/lane, lane owns 4 fixed output columns). Edge index k0+u is
// WAVE-UNIFORM -> alpha/row broadcast via v_readlane to SGPR (VALU; kills
// the ds_bpermute storm) and row base address computes on the free SALU
// pipe. ~11 wave-inst/edge vs 21 before; no cross-half final reduce.
// Degree padded to x8; pad loads hit H row 0 (L1/L2-resident, no HBM cost).
__global__ __launch_bounds__(64) void gat_gather(
    const u32* __restrict__ pos2, const u32* __restrict__ degp,
    const int* __restrict__ psrc, const float* __restrict__ a_src,
    const float* __restrict__ a_dst, const u16* __restrict__ Hfb,
    const float* __restrict__ bias3, const float* __restrict__ Wh,
    const float* __restrict__ bh, int layer, u16* __restrict__ x2b,
    float* __restrict__ out)
{
    int n = blockIdx.x;
    int lane = threadIdx.x;

    u32 o0 = pos2[n];
    u32 dp = degp[n];
    int d0 = dp & 255, d1 = (dp >> 8) & 255;
    int dtot = d0 + d1 + ((dp >> 16) & 255);
    if (dtot > 64) dtot = 64;                        // unreachable

    // lane j: edge j's score + exp (invalid lanes: rs=0, alpha=0)
    int  j     = lane;
    bool valid = j < dtot;
    int  tj    = (j >= d0) + (j >= d0 + d1);
    int  rs    = valid ? psrc[o0 + j] : 0;
    float as   = a_src[rs];                          // 600 KB array: L2-hit
    float adn  = a_dst[tj * GAT_N + n];
    float e = as + adn;
    e = (e > 0.f) ? e : GAT_SLOPE * e;
    float ex = valid ? __expf(e) : 0.f;

    // segmented (per-type) sums: DPP within 16 lanes, shfl across rows
    float s0 = (tj == 0) ? ex : 0.f;
    float s1 = (tj == 1) ? ex : 0.f;
    float s2 = (tj == 2) ? ex : 0.f;
    s0 = sum16(s0); s1 = sum16(s1); s2 = sum16(s2);
    #pragma unroll
    for (int d = 16; d < 64; d <<= 1) {
        s0 += __shfl_xor(s0, d);
        s1 += __shfl_xor(s1, d);
        s2 += __shfl_xor(s2, d);
    }
    float den = (tj == 0) ? s0 : ((tj == 1) ? s1 : s2);
    float alv = valid ? ex / den : 0.f;              // this lane's alpha

    // wave-cooperative FMA: 8 edges per iter, 8x 512 B rows in flight
    float r[4] = {};
    const u16* Hl = Hfb + lane * 4;                  // lane's 8 B column slot
    int av = __builtin_bit_cast(int, alv);
    int dpad = (dtot + 7) & ~7;
    for (int k0 = 0; k0 < dpad; k0 += 8) {
        float al[8]; u32x2 w[8];
        #pragma unroll
        for (int u = 0; u < 8; ++u) {
            int rv = __builtin_amdgcn_readlane(rs, k0 + u);      // SGPR
            al[u]  = __builtin_bit_cast(float,
                         __builtin_amdgcn_readlane(av, k0 + u)); // SGPR
            w[u] = *(const u32x2*)(Hl + (size_t)rv * GAT_D);
        }
        #pragma unroll
        for (int u = 0; u < 8; ++u) {
            r[0] += al[u] * lo16(w[u].x);
            r[1] += al[u] * hi16(w[u].x);
            r[2] += al[u] * lo16(w[u].y);
            r[3] += al[u] * hi16(w[u].y);
        }
    }

    int c0 = lane * 4;
    const float* b3 = bias3 + layer * GAT_D;
    float v[4];
    #pragma unroll
    for (int i = 0; i < 4; ++i) v[i] = fmaxf(r[i] + b3[c0 + i], 0.f);

    if (layer == 0) {
        u16 pk[4];
        #pragma unroll
        for (int i = 0; i < 4; ++i) pk[i] = f2bf(v[i]);
        *(ushort4*)(x2b + (size_t)n * GAT_D + c0) = *(ushort4*)pk;
    } else {
        float wsum = 0.f;
        #pragma unroll
        for (int i = 0; i < 4; ++i) wsum += v[i] * Wh[c0 + i];
        wsum = sum16(wsum);
        wsum += __shfl_xor(wsum, 16);
        wsum += __shfl_xor(wsum, 32);
        if (lane == 0) out[n] = 1.0f / (1.0f + __expf(-(wsum + bh[0])));
    }
}

// retain harness-expected symbol
__global__ void PyGTypeSpecificGAT_80075370266775_kernel() {}

extern "C" void kernel_launch(void* const* d_in, const int* in_sizes, int n_in,
                              void* d_out, int out_size, void* d_ws, size_t ws_size,
                              hipStream_t stream)
{
    (void)in_sizes; (void)n_in; (void)out_size; (void)ws_size;
    const float* z   = (const float*)d_in[0];
    const int*   ei  = (const int*)d_in[1];
    const float* W1  = (const float*)d_in[2];
    const float* as1 = (const float*)d_in[3];
    const float* ad1 = (const float*)d_in[4];
    const float* b1  = (const float*)d_in[5];
    const float* W2  = (const float*)d_in[6];
    const float* as2 = (const float*)d_in[7];
    const float* ad2 = (const float*)d_in[8];
    const float* b2  = (const float*)d_in[9];
    const float* Wh  = (const float*)d_in[10];
    const float* bh  = (const float*)d_in[11];
    float* out = (float*)d_out;

    // ---- workspace (~147 MB; >=156 MB proven). zb/x2b must not be last
    // (gemm staging over-reads <=24 KB past row 50000).
    char* p = (char*)d_ws;
    u16*  Hfb  = (u16*)p;  p += (size_t)GAT_T * GAT_N * GAT_D * 2;  // 76.8 MB
    u16*  x2b  = (u16*)p;  p += (size_t)GAT_N * GAT_D * 2;          // 25.6 MB
    u16*  zb   = (u16*)p;  p += (size_t)GAT_N * GAT_D * 2;          // 25.6 MB
    float* part_src = (float*)p; p += (size_t)24 * GAT_N * 4;       // 4.8 MB
    float* part_dst = (float*)p; p += (size_t)24 * GAT_N * 4;       // 4.8 MB
    float* a_src = (float*)p; p += (size_t)GAT_B * 4;               // 0.6 MB
    float* a_dst = (float*)p; p += (size_t)GAT_B * 4;               // 0.6 MB
    u32*  cnt  = (u32*)p;  p += (size_t)GAT_B * 4;
    u32*  cur  = (u32*)p;  p += (size_t)GAT_B * 4;
    u32*  pos2 = (u32*)p;  p += (size_t)GAT_N * 4;
    u32*  degp = (u32*)p;  p += (size_t)GAT_N * 4;
    u32*  total = (u32*)p; p += 256;
    int*  psrc = (int*)p;  p += (size_t)GAT_TOTE * 4;               // 3 MB
    u16*  WT1b = (u16*)p;  p += (size_t)GAT_COLS * GAT_D * 2;
    u16*  WT2b = (u16*)p;  p += (size_t)GAT_COLS * GAT_D * 2;
    float* bias3 = (float*)p; p += 2 * GAT_D * 4;

    const int NODE_BLKS = (GAT_N + 255) / 256;              // 196
    const int EDGE_BLKS = (GAT_TOTE + 255) / 256;           // 2930
    const int BUCK_BLKS = (GAT_B + 255) / 256;              // 586
    const int PREP_BLKS = (GAT_N * GAT_D / 4 + 255) / 256;  // 12500

    gat_prep<<<PREP_BLKS, 256, 0, stream>>>(W1, W2, z, b1, b2, WT1b, WT2b,
                                            zb, cnt, total, bias3);
    gat_hist<<<EDGE_BLKS, 256, 0, stream>>>(ei, cnt);
    gat_alloc<<<NODE_BLKS, 256, 0, stream>>>(cnt, pos2, degp, cur, total);
    gat_scatter<<<EDGE_BLKS, 256, 0, stream>>>(ei, cur, psrc);

    // 49 slab-groups of 8 x 6 col tiles = 2352 blocks (6 tail blocks idle)
    const int GEMM_BLKS = 49 * 48;

    for (int layer = 0; layer < 2; ++layer) {
        const u16*   A   = (layer == 0) ? zb   : x2b;
        const u16*   WTb = (layer == 0) ? WT1b : WT2b;
        const float* as_ = (layer == 0) ? as1  : as2;
        const float* ad_ = (layer == 0) ? ad1  : ad2;

        gat_gemm<<<GEMM_BLKS, 512, 0, stream>>>(A, WTb, Hfb, as_, ad_,
                                                part_src, part_dst);
        gat_sum<<<BUCK_BLKS, 256, 0, stream>>>(part_src, part_dst,
                                               a_src, a_dst);
        gat_gather<<<GAT_N, 64, 0, stream>>>(pos2, degp, psrc,
                                             a_src, a_dst, Hfb, bias3,
                                             Wh, bh, layer, x2b, out);
    }
}

// Round 7
// 404.601 us; speedup vs baseline: 1.0765x; 1.0131x over previous
//
#include <hip/hip_runtime.h>

#define GAT_N 50000
#define GAT_D 256
#define GAT_T 3
#define GAT_E 250000
#define GAT_B (GAT_T*GAT_N)      // 150000 (node,type) buckets
#define GAT_TOTE (GAT_T*GAT_E)   // 750000 edges total
#define GAT_COLS (GAT_T*GAT_D)   // 768 fused output columns
#define GAT_SLOPE 0.2f

typedef unsigned short u16;
typedef unsigned int u32;
typedef __attribute__((ext_vector_type(8))) short s16x8;     // raw bf16 storage
typedef __attribute__((ext_vector_type(8))) __bf16 bf16x8;   // MFMA operand
typedef __attribute__((ext_vector_type(4))) float f32x4;
typedef __attribute__((ext_vector_type(2))) u32 u32x2;

__device__ __forceinline__ u16 f2bf(float f) {
    u32 x = __builtin_bit_cast(u32, f);
    u32 r = (x + 0x7fffu + ((x >> 16) & 1u)) >> 16;   // RNE
    return (u16)r;
}
__device__ __forceinline__ float lo16(u32 w) {
    return __builtin_bit_cast(float, w << 16);
}
__device__ __forceinline__ float hi16(u32 w) {
    return __builtin_bit_cast(float, w & 0xffff0000u);
}

// ---- DPP butterfly adds (VALU pipe, NOT ds_swizzle/LDS pipe) --------------
// xor1 = quad_perm(1,0,3,2)=0xB1 (exact), xor2 = quad_perm(2,3,0,1)=0x4E
// (exact), row_half_mirror(0x141) = ^7 == ^4 after 4-lane uniformity,
// row_mirror(0x140) = ^15 == ^8 after 8-lane uniformity. Same masks, same
// add order as a __shfl_xor butterfly -> bit-identical results.
template<int CTRL>
__device__ __forceinline__ float dppadd(float x) {
    int y = __builtin_amdgcn_update_dpp(0, __builtin_bit_cast(int, x),
                                        CTRL, 0xf, 0xf, true);
    return x + __builtin_bit_cast(float, y);
}
__device__ __forceinline__ float sum16(float x) {   // reduce within 16 lanes
    x = dppadd<0xB1>(x);
    x = dppadd<0x4E>(x);
    x = dppadd<0x141>(x);
    x = dppadd<0x140>(x);
    return x;
}

// ---- fused prep: W1/W2 -> bf16 transposed, z -> bf16, cnt/total -> 0, bias3
__global__ void gat_prep(const float* __restrict__ W1, const float* __restrict__ W2,
                         const float* __restrict__ z, const float* __restrict__ b1,
                         const float* __restrict__ b2, u16* __restrict__ WT1b,
                         u16* __restrict__ WT2b, u16* __restrict__ zb,
                         u32* __restrict__ cnt, u32* __restrict__ total,
                         float* __restrict__ bias3)
{
    int idx = blockIdx.x * 256 + threadIdx.x;
    if (idx == 0) *total = 0u;
    if (idx < GAT_T * GAT_D * GAT_D) {               // 196608
        int t = idx >> 16, r = idx & 65535;
        int d = r >> 8, h = r & 255;
        WT1b[t * 65536 + h * 256 + d] = f2bf(W1[idx]);
        WT2b[t * 65536 + h * 256 + d] = f2bf(W2[idx]);
    }
    if (idx < GAT_B) cnt[idx] = 0u;
    if (idx < 2 * GAT_D) {
        const float* bb = (idx < GAT_D) ? b1 : b2;
        int c = idx & 255;
        bias3[idx] = bb[c] + bb[GAT_D + c] + bb[2 * GAT_D + c];
    }
    if (idx < GAT_N * GAT_D / 4) {
        f32x4 v = ((const f32x4*)z)[idx];
        ushort4 pk;
        pk.x = f2bf(v.x); pk.y = f2bf(v.y); pk.z = f2bf(v.z); pk.w = f2bf(v.w);
        ((ushort4*)zb)[idx] = pk;
    }
}

// ================= CSR build: per-node contiguous triples ===================
__global__ void gat_hist(const int* __restrict__ ei, u32* __restrict__ cnt) {
    int idx = blockIdx.x * 256 + threadIdx.x;
    if (idx >= GAT_TOTE) return;
    int t = idx / GAT_E;
    int e = idx - t * GAT_E;
    int dst = ei[t * 2 * GAT_E + GAT_E + e];
    atomicAdd(&cnt[dst * GAT_T + t], 1u);
}

// one thread per NODE: contiguous slab for its 3 type-segments
__global__ void gat_alloc(const u32* __restrict__ cnt, u32* __restrict__ pos2,
                          u32* __restrict__ degp, u32* __restrict__ cur,
                          u32* __restrict__ total)
{
    int n = blockIdx.x * 256 + threadIdx.x;
    if (n >= GAT_N) return;
    u32 c0 = cnt[3 * n], c1 = cnt[3 * n + 1], c2 = cnt[3 * n + 2];
    u32 p = atomicAdd(total, c0 + c1 + c2);
    pos2[n] = p;
    degp[n] = c0 | (c1 << 8) | (c2 << 16);
    cur[3 * n]     = p;
    cur[3 * n + 1] = p + c0;
    cur[3 * n + 2] = p + c0 + c1;
}

// psrc stores ABSOLUTE H row (t*N+src)
__global__ void gat_scatter(const int* __restrict__ ei, u32* __restrict__ cur,
                            int* __restrict__ psrc)
{
    int idx = blockIdx.x * 256 + threadIdx.x;
    if (idx >= GAT_TOTE) return;
    int t = idx / GAT_E;
    int e = idx - t * GAT_E;
    int src = ei[t * 2 * GAT_E + e];
    int dst = ei[t * 2 * GAT_E + GAT_E + e];
    u32 slot = atomicAdd(&cur[dst * GAT_T + t], 1u);
    psrc[slot] = t * GAT_N + src;
}

// ================= LDS-staged MFMA GEMM (XOR-swizzled) + partial attn dots ==
// Swizzle: LDS[row][chunk j] = G[row][j ^ (row&7)] via permuted per-lane
// global source addr (keeps global_load_lds wave-uniform dest + coalescing).
// Grid swizzle: lin = (r/8)*48 + c*8 + (r%8) -> col siblings share an XCD.
// Dbuf K-loop, counted vmcnt (r3). 512-thread / 8-wave blocks (r4).
// Epilogue-2 reduction via DPP (r5: LDS-pipe relief; gemm 65.5 -> <61).
__global__ __launch_bounds__(512, 4) void gat_gemm(
    const u16* __restrict__ A, const u16* __restrict__ WTb,
    u16* __restrict__ H, const float* __restrict__ as_in,
    const float* __restrict__ ad_in, float* __restrict__ part_src,
    float* __restrict__ part_dst)
{
    // decode XCD-grouped swizzle
    int lin = blockIdx.x;
    int g   = lin / 48;
    int rem = lin - g * 48;
    int bc  = rem >> 3;                 // col tile 0..5
    int br  = (g << 3) + (rem & 7);     // row slab 0..390
    if (br >= 391) return;

    __shared__ u16 Als[2][128 * 64];   // 2 x 16 KB
    __shared__ u16 Bls[2][128 * 64];   // 2 x 16 KB
    int tid  = threadIdx.x;
    int wave = tid >> 6, lane = tid & 63;
    int quad = lane >> 4, l16 = lane & 15;
    int wm = wave & 1, wn = wave >> 1;       // wm: row half, wn: col quarter
    int lrow = lane >> 3;                    // 0..7
    int swz  = ((lane & 7) ^ lrow) * 8;      // swizzled k-offset (u16)

    size_t arow0 = (size_t)br * 128;
    size_t brow0 = (size_t)bc * 128;

    // stage K-chunk ks into buffer buf: 4 global_load_lds per wave
    // (2 x 8-row groups x {A,B}); wave w covers rows [w*16, w*16+16).
    auto STAGE = [&](int buf, int ks) {
        int k0 = ks * 64;
        #pragma unroll
        for (int r = 0; r < 2; ++r) {
            int srow = wave * 16 + r * 8 + lrow;
            const u16* gA = A   + (arow0 + srow) * GAT_D + k0 + swz;
            const u16* gB = WTb + (brow0 + srow) * GAT_D + k0 + swz;
            u16* lA = &Als[buf][wave * 1024 + r * 512];   // wave-uniform dest
            u16* lB = &Bls[buf][wave * 1024 + r * 512];
#if defined(__has_builtin) && __has_builtin(__builtin_amdgcn_global_load_lds)
            __builtin_amdgcn_global_load_lds(
                (const __attribute__((address_space(1))) void*)gA,
                (__attribute__((address_space(3))) void*)lA, 16, 0, 0);
            __builtin_amdgcn_global_load_lds(
                (const __attribute__((address_space(1))) void*)gB,
                (__attribute__((address_space(3))) void*)lB, 16, 0, 0);
#else
            *(s16x8*)(lA + lane * 8) = *(const s16x8*)gA;
            *(s16x8*)(lB + lane * 8) = *(const s16x8*)gB;
#endif
        }
    };

    f32x4 acc[4][2] = {};

    STAGE(0, 0);
    #pragma unroll
    for (int ks = 0; ks < 4; ++ks) {
        int cur = ks & 1;
        if (ks < 3) {
            STAGE(cur ^ 1, ks + 1);
            // wait for buf[cur]'s 4 loads; buf[cur^1]'s 4 stay in flight
            asm volatile("s_waitcnt vmcnt(4)" ::: "memory");
        } else {
            asm volatile("s_waitcnt vmcnt(0)" ::: "memory");
        }
        __builtin_amdgcn_s_barrier();     // all waves' stage of cur complete

        #pragma unroll
        for (int kk = 0; kk < 2; ++kk) {
            int csw8 = ((kk * 4 + quad) ^ (l16 & 7)) * 8;   // row&7 == l16&7
            bf16x8 af[4], bf[2];
            #pragma unroll
            for (int i = 0; i < 4; ++i)
                af[i] = __builtin_bit_cast(bf16x8,
                    *(const s16x8*)(&Als[cur][(wm * 64 + i * 16 + l16) * 64 + csw8]));
            #pragma unroll
            for (int j = 0; j < 2; ++j)
                bf[j] = __builtin_bit_cast(bf16x8,
                    *(const s16x8*)(&Bls[cur][(wn * 32 + j * 16 + l16) * 64 + csw8]));
            #pragma unroll
            for (int i = 0; i < 4; ++i)
                #pragma unroll
                for (int j = 0; j < 2; ++j)
                    acc[i][j] = __builtin_amdgcn_mfma_f32_16x16x32_bf16(
                        af[i], bf[j], acc[i][j], 0, 0, 0);
        }
        if (ks < 3)
            __builtin_amdgcn_s_barrier(); // reads of cur done before re-stage
    }

    // epilogue 1: H write (C/D col=l16, row=quad*4+reg)
    int gcol0 = bc * 128 + wn * 32;
    int t   = gcol0 >> 8;
    int ch0 = gcol0 & 255;
    int c32 = bc * 4 + wn;                       // 0..23 (type = c32>>3)
    u16* Ht = H + (size_t)t * GAT_N * GAT_D;
    int rowb = br * 128 + wm * 64 + quad * 4;
    #pragma unroll
    for (int i = 0; i < 4; ++i) {
        #pragma unroll
        for (int j = 0; j < 2; ++j) {
            int ch = ch0 + j * 16 + l16;
            #pragma unroll
            for (int r = 0; r < 4; ++r) {
                int row = rowb + i * 16 + r;
                if (row < GAT_N) Ht[(size_t)row * GAT_D + ch] = f2bf(acc[i][j][r]);
            }
        }
    }

    // epilogue 2: attn dot partials (deterministic, no atomics, no pre-zero)
    // reduction over the 16 l16 lanes via DPP (VALU), not shfl (LDS).
    float asv[2], adv[2];
    #pragma unroll
    for (int j = 0; j < 2; ++j) {
        int ch = ch0 + j * 16 + l16;
        asv[j] = as_in[t * GAT_D + ch];
        adv[j] = ad_in[t * GAT_D + ch];
    }
    #pragma unroll
    for (int i = 0; i < 4; ++i) {
        float ps[4] = {}, pd[4] = {};
        #pragma unroll
        for (int j = 0; j < 2; ++j) {
            f32x4 a = acc[i][j];
            #pragma unroll
            for (int r = 0; r < 4; ++r) {
                ps[r] += a[r] * asv[j];
                pd[r] += a[r] * adv[j];
            }
        }
        #pragma unroll
        for (int r = 0; r < 4; ++r) {
            ps[r] = sum16(ps[r]);
            pd[r] = sum16(pd[r]);
        }
        if (l16 == 0) {
            int row = rowb + i * 16;
            #pragma unroll
            for (int r = 0; r < 4; ++r) {
                if (row + r < GAT_N) {
                    part_src[(size_t)c32 * GAT_N + row + r] = ps[r];
                    part_dst[(size_t)c32 * GAT_N + row + r] = pd[r];
                }
            }
        }
    }
}

// ---- reduce 8 col-chunk partials -> a_src/a_dst[t*N+n] (coalesced) --------
__global__ void gat_sum(const float* __restrict__ part_src,
                        const float* __restrict__ part_dst,
                        float* __restrict__ a_src, float* __restrict__ a_dst)
{
    int idx = blockIdx.x * 256 + threadIdx.x;        // [0, 3N)
    if (idx >= GAT_B) return;
    int t = idx / GAT_N;
    int n = idx - t * GAT_N;
    const float* ps = part_src + (size_t)8 * t * GAT_N;
    const float* pd = part_dst + (size_t)8 * t * GAT_N;
    float s = 0.f, d = 0.f;
    #pragma unroll
    for (int c = 0; c < 8; ++c) {
        s += ps[(size_t)c * GAT_N + n];
        d += pd[(size_t)c * GAT_N + n];
    }
    a_src[idx] = s;
    a_dst[idx] = d;
}

// ================= gather: wave-per-edge readlane + issue-early pipeline ====
// r6: one wave per dst node; lane owns 4 fixed output cols; edge index is
// wave-uniform -> alpha/row broadcast via v_readlane (SGPR, no LDS pipe).
// r7: H-row loads depend ONLY on rs (psrc), not on softmax -- batch-0 loads
// issue BEFORE the softmax (expf + reductions hide under their latency),
// and the FMA loop prefetches batch k+1's rows while FMA-ing batch k
// (T14 issue-early/consume-late; dynamic trip count blocked compiler
// pipelining). All register buffers statically indexed.
__global__ __launch_bounds__(64) void gat_gather(
    const u32* __restrict__ pos2, const u32* __restrict__ degp,
    const int* __restrict__ psrc, const float* __restrict__ a_src,
    const float* __restrict__ a_dst, const u16* __restrict__ Hfb,
    const float* __restrict__ bias3, const float* __restrict__ Wh,
    const float* __restrict__ bh, int layer, u16* __restrict__ x2b,
    float* __restrict__ out)
{
    int n = blockIdx.x;
    int lane = threadIdx.x;

    u32 o0 = pos2[n];
    u32 dp = degp[n];
    int d0 = dp & 255, d1 = (dp >> 8) & 255;
    int dtot = d0 + d1 + ((dp >> 16) & 255);
    if (dtot > 64) dtot = 64;                        // unreachable

    // lane j: edge j's source row (invalid lanes: row 0, alpha will be 0)
    int  j     = lane;
    bool valid = j < dtot;
    int  tj    = (j >= d0) + (j >= d0 + d1);
    int  rs    = valid ? psrc[o0 + j] : 0;

    // issue the dependent score loads FIRST...
    float as   = a_src[rs];                          // 600 KB array: L2-hit
    float adn  = a_dst[tj * GAT_N + n];

    // ...then IMMEDIATELY issue batch-0 H-row loads (independent of softmax)
    const u16* Hl = Hfb + lane * 4;                  // lane's 8 B column slot
    u32x2 w[8];
    #pragma unroll
    for (int u = 0; u < 8; ++u) {
        int rv = __builtin_amdgcn_readlane(rs, u);   // SGPR broadcast
        w[u] = *(const u32x2*)(Hl + (size_t)rv * GAT_D);
    }

    // softmax (hides under the H-load latency above)
    float e = as + adn;
    e = (e > 0.f) ? e : GAT_SLOPE * e;
    float ex = valid ? __expf(e) : 0.f;

    float s0 = (tj == 0) ? ex : 0.f;
    float s1 = (tj == 1) ? ex : 0.f;
    float s2 = (tj == 2) ? ex : 0.f;
    s0 = sum16(s0); s1 = sum16(s1); s2 = sum16(s2);
    #pragma unroll
    for (int d = 16; d < 64; d <<= 1) {
        s0 += __shfl_xor(s0, d);
        s1 += __shfl_xor(s1, d);
        s2 += __shfl_xor(s2, d);
    }
    float den = (tj == 0) ? s0 : ((tj == 1) ? s1 : s2);
    float alv = valid ? ex / den : 0.f;              // this lane's alpha
    int av = __builtin_bit_cast(int, alv);

    // pipelined FMA: consume batch k from w while prefetching batch k+1
    float r[4] = {};
    int dpad = (dtot + 7) & ~7;
    for (int k0 = 0; ; k0 += 8) {
        float al[8]; u32x2 wc[8];
        #pragma unroll
        for (int u = 0; u < 8; ++u) {
            wc[u] = w[u];                            // SSA rename, not a copy
            al[u] = __builtin_bit_cast(float,
                        __builtin_amdgcn_readlane(av, k0 + u));
        }
        bool more = (k0 + 8 < dpad);
        if (more) {
            #pragma unroll
            for (int u = 0; u < 8; ++u) {
                int rv = __builtin_amdgcn_readlane(rs, k0 + 8 + u);
                w[u] = *(const u32x2*)(Hl + (size_t)rv * GAT_D);
            }
        }
        #pragma unroll
        for (int u = 0; u < 8; ++u) {
            r[0] += al[u] * lo16(wc[u].x);
            r[1] += al[u] * hi16(wc[u].x);
            r[2] += al[u] * lo16(wc[u].y);
            r[3] += al[u] * hi16(wc[u].y);
        }
        if (!more) break;
    }

    int c0 = lane * 4;
    const float* b3 = bias3 + layer * GAT_D;
    float v[4];
    #pragma unroll
    for (int i = 0; i < 4; ++i) v[i] = fmaxf(r[i] + b3[c0 + i], 0.f);

    if (layer == 0) {
        u16 pk[4];
        #pragma unroll
        for (int i = 0; i < 4; ++i) pk[i] = f2bf(v[i]);
        *(ushort4*)(x2b + (size_t)n * GAT_D + c0) = *(ushort4*)pk;
    } else {
        float wsum = 0.f;
        #pragma unroll
        for (int i = 0; i < 4; ++i) wsum += v[i] * Wh[c0 + i];
        wsum = sum16(wsum);
        wsum += __shfl_xor(wsum, 16);
        wsum += __shfl_xor(wsum, 32);
        if (lane == 0) out[n] = 1.0f / (1.0f + __expf(-(wsum + bh[0])));
    }
}

// retain harness-expected symbol
__global__ void PyGTypeSpecificGAT_80075370266775_kernel() {}

extern "C" void kernel_launch(void* const* d_in, const int* in_sizes, int n_in,
                              void* d_out, int out_size, void* d_ws, size_t ws_size,
                              hipStream_t stream)
{
    (void)in_sizes; (void)n_in; (void)out_size; (void)ws_size;
    const float* z   = (const float*)d_in[0];
    const int*   ei  = (const int*)d_in[1];
    const float* W1  = (const float*)d_in[2];
    const float* as1 = (const float*)d_in[3];
    const float* ad1 = (const float*)d_in[4];
    const float* b1  = (const float*)d_in[5];
    const float* W2  = (const float*)d_in[6];
    const float* as2 = (const float*)d_in[7];
    const float* ad2 = (const float*)d_in[8];
    const float* b2  = (const float*)d_in[9];
    const float* Wh  = (const float*)d_in[10];
    const float* bh  = (const float*)d_in[11];
    float* out = (float*)d_out;

    // ---- workspace (~147 MB; >=156 MB proven). zb/x2b must not be last
    // (gemm staging over-reads <=24 KB past row 50000).
    char* p = (char*)d_ws;
    u16*  Hfb  = (u16*)p;  p += (size_t)GAT_T * GAT_N * GAT_D * 2;  // 76.8 MB
    u16*  x2b  = (u16*)p;  p += (size_t)GAT_N * GAT_D * 2;          // 25.6 MB
    u16*  zb   = (u16*)p;  p += (size_t)GAT_N * GAT_D * 2;          // 25.6 MB
    float* part_src = (float*)p; p += (size_t)24 * GAT_N * 4;       // 4.8 MB
    float* part_dst = (float*)p; p += (size_t)24 * GAT_N * 4;       // 4.8 MB
    float* a_src = (float*)p; p += (size_t)GAT_B * 4;               // 0.6 MB
    float* a_dst = (float*)p; p += (size_t)GAT_B * 4;               // 0.6 MB
    u32*  cnt  = (u32*)p;  p += (size_t)GAT_B * 4;
    u32*  cur  = (u32*)p;  p += (size_t)GAT_B * 4;
    u32*  pos2 = (u32*)p;  p += (size_t)GAT_N * 4;
    u32*  degp = (u32*)p;  p += (size_t)GAT_N * 4;
    u32*  total = (u32*)p; p += 256;
    int*  psrc = (int*)p;  p += (size_t)GAT_TOTE * 4;               // 3 MB
    u16*  WT1b = (u16*)p;  p += (size_t)GAT_COLS * GAT_D * 2;
    u16*  WT2b = (u16*)p;  p += (size_t)GAT_COLS * GAT_D * 2;
    float* bias3 = (float*)p; p += 2 * GAT_D * 4;

    const int NODE_BLKS = (GAT_N + 255) / 256;              // 196
    const int EDGE_BLKS = (GAT_TOTE + 255) / 256;           // 2930
    const int BUCK_BLKS = (GAT_B + 255) / 256;              // 586
    const int PREP_BLKS = (GAT_N * GAT_D / 4 + 255) / 256;  // 12500

    gat_prep<<<PREP_BLKS, 256, 0, stream>>>(W1, W2, z, b1, b2, WT1b, WT2b,
                                            zb, cnt, total, bias3);
    gat_hist<<<EDGE_BLKS, 256, 0, stream>>>(ei, cnt);
    gat_alloc<<<NODE_BLKS, 256, 0, stream>>>(cnt, pos2, degp, cur, total);
    gat_scatter<<<EDGE_BLKS, 256, 0, stream>>>(ei, cur, psrc);

    // 49 slab-groups of 8 x 6 col tiles = 2352 blocks (6 tail blocks idle)
    const int GEMM_BLKS = 49 * 48;

    for (int layer = 0; layer < 2; ++layer) {
        const u16*   A   = (layer == 0) ? zb   : x2b;
        const u16*   WTb = (layer == 0) ? WT1b : WT2b;
        const float* as_ = (layer == 0) ? as1  : as2;
        const float* ad_ = (layer == 0) ? ad1  : ad2;

        gat_gemm<<<GEMM_BLKS, 512, 0, stream>>>(A, WTb, Hfb, as_, ad_,
                                                part_src, part_dst);
        gat_sum<<<BUCK_BLKS, 256, 0, stream>>>(part_src, part_dst,
                                               a_src, a_dst);
        gat_gather<<<GAT_N, 64, 0, stream>>>(pos2, degp, psrc,
                                             a_src, a_dst, Hfb, bias3,
                                             Wh, bh, layer, x2b, out);
    }
}